// Round 1
// baseline (10071.678 us; speedup 1.0000x reference)
//
#include <hip/hip_runtime.h>
#include <cstdint>
#include <cstddef>

// ---------------------------------------------------------------------------
// PCFG-RNN forward on MI355X.
// k1: persistent 256-block kernel with software grid barriers:
//     P0 (embed gather + gi_lex GEMM) -> 64 sequential lex-GRU steps ->
//     P2 (syn_hids + per-diag-cell precompute) ->
//     63 chart levels x 2 phases (A': score/argmax/hB/giW/gR, D2: hAc/ghA).
//     Per-cell precompute (gR, giW, hAc, ghA) makes hB fully elementwise,
//     giving the minimal 2 syncs/level.
// k2: tiled 64x64 GEMM lex_hids @ emb^T + column log_softmax (column-local),
//     coalesced writes, per-row max via ordered-uint atomicMax.
// k3: final scalars.
// ---------------------------------------------------------------------------

#define NBLK 256
#define NTHR 256
#define HH   512
#define H3   1536
#define NTOK 64
#define VOCAB 50257
#define NCELLS 2080

// ---- ws layout (float offsets) ----
#define OFF_LP      0                          // 64*64 chart log-probs (zeroed)
#define OFF_H0      4096                       // 512 zeros
#define OFF_GILEX   4608                       // 64*1536
#define OFF_LEXH    (OFF_GILEX + NTOK*H3)      // 64*512
#define OFF_ROWMAX  (OFF_LEXH + NTOK*HH)       // 64 (as uint, ordered encoding)
#define OFF_SYNC    (OFF_ROWMAX + 64)          // barrier cnt/gen
#define OFF_CELLH   (OFF_SYNC + 64)
#define OFF_CELLGR  (OFF_CELLH  + NCELLS*HH)
#define OFF_CELLHA  (OFF_CELLGR + NCELLS*HH)
#define OFF_CELLGIW (OFF_CELLHA + NCELLS*HH)
#define OFF_CELLGHA (OFF_CELLGIW + NCELLS*H3)
#define WS_FLOATS   (OFF_CELLGHA + NCELLS*H3)  // ~9.72M floats = ~38.9 MB

__device__ __forceinline__ int cid(int i, int j) { return ((j*(j+1)) >> 1) + i; }

__device__ __forceinline__ float sigf(float x) { return 1.f / (1.f + expf(-x)); }

__device__ __forceinline__ float logsigf(float x) {
  return fminf(x, 0.f) - log1pf(expf(-fabsf(x)));
}

__device__ __forceinline__ float wredsum(float s) {
#pragma unroll
  for (int off = 32; off >= 1; off >>= 1) s += __shfl_xor(s, off);
  return s;
}

// 512-element dot product across one 64-lane wave; result on all lanes.
__device__ __forceinline__ float dot512(const float* __restrict__ a,
                                        const float* __restrict__ b) {
  const int lane = threadIdx.x & 63;
  const float4* a4 = (const float4*)a;
  const float4* b4 = (const float4*)b;
  float4 x0 = a4[lane], x1 = a4[lane + 64];
  float4 y0 = b4[lane], y1 = b4[lane + 64];
  float s = x0.x*y0.x + x0.y*y0.y + x0.z*y0.z + x0.w*y0.w
          + x1.x*y1.x + x1.y*y1.y + x1.z*y1.z + x1.w*y1.w;
  return wredsum(s);
}

// Software grid barrier (generation-tagged). cnt/gen zeroed by memset each launch.
__device__ __forceinline__ void gbar(int* cnt, int* gen) {
  __syncthreads();
  if (threadIdx.x == 0) {
    __threadfence();
    int g = __hip_atomic_load(gen, __ATOMIC_RELAXED, __HIP_MEMORY_SCOPE_AGENT);
    int p = __hip_atomic_fetch_add(cnt, 1, __ATOMIC_ACQ_REL, __HIP_MEMORY_SCOPE_AGENT);
    if (p == NBLK - 1) {
      __hip_atomic_store(cnt, 0, __ATOMIC_RELAXED, __HIP_MEMORY_SCOPE_AGENT);
      __hip_atomic_fetch_add(gen, 1, __ATOMIC_RELEASE, __HIP_MEMORY_SCOPE_AGENT);
    } else {
      while (__hip_atomic_load(gen, __ATOMIC_RELAXED, __HIP_MEMORY_SCOPE_AGENT) == g)
        __builtin_amdgcn_s_sleep(1);
    }
    __threadfence();
  }
  __syncthreads();
}

__global__ __launch_bounds__(NTHR, 1) void pcfg_k1(
    const int* __restrict__ tokens, const float* __restrict__ emb,
    const float* __restrict__ lexWih, const float* __restrict__ lexWhh,
    const float* __restrict__ lexbih, const float* __restrict__ lexbhh,
    const float* __restrict__ posW,   const float* __restrict__ posb,
    const float* __restrict__ synWih, const float* __restrict__ synWhh,
    const float* __restrict__ synbih, const float* __restrict__ synbhh,
    const float* __restrict__ composW, float* __restrict__ ws)
{
  __shared__ __align__(16) float sv[HH];   // hB / hAc staging
  __shared__ float ssc[64];                // split scores
  __shared__ float ghv[8];                 // lex gh values
  __shared__ int   skb;
  __shared__ float sbest;

  float* lp    = ws + OFF_LP;
  float* h0    = ws + OFF_H0;
  float* gilex = ws + OFF_GILEX;
  float* lexh  = ws + OFF_LEXH;
  unsigned* rowmax = (unsigned*)(ws + OFF_ROWMAX);
  int*   snc   = (int*)(ws + OFF_SYNC);
  float* cH   = ws + OFF_CELLH;
  float* cGR  = ws + OFF_CELLGR;
  float* cHA  = ws + OFF_CELLHA;
  float* cGIW = ws + OFF_CELLGIW;
  float* cGHA = ws + OFF_CELLGHA;

  const int bid = blockIdx.x, tid = threadIdx.x;
  const int wv = tid >> 6, lane = tid & 63;
  const int gw = (bid << 2) | wv;          // global wave id 0..1023

  // ---------------- P0: zero lp/h0, init rowmax, gi_lex GEMM ----------------
  for (int i = bid*NTHR + tid; i < OFF_GILEX; i += NBLK*NTHR) ws[i] = 0.f;
  if (bid == 0 && tid < 64) rowmax[tid] = 0u;
  for (int task = gw; task < NTOK*H3; task += NBLK*4) {
    int t = task / H3, r = task - t*H3;
    float v = dot512(lexWih + (size_t)r*HH, emb + (size_t)tokens[t]*HH) + lexbih[r];
    if (lane == 0) gilex[task] = v;
  }
  gbar(snc, snc + 1);

  // ---------------- P1: 64 sequential lex GRU steps ----------------
  for (int t = 0; t < NTOK; ++t) {
    const float* hp = (t == 0) ? h0 : (lexh + (size_t)(t-1)*HH);
    for (int d = wv; d < 6; d += 4) {              // 2 cols/block * 3 gates
      int gate = d >> 1, cl = d & 1;
      int row = gate*HH + (bid*2 + cl);
      float v = dot512(lexWhh + (size_t)row*HH, hp) + lexbhh[row];
      if (lane == 0) ghv[d] = v;
    }
    __syncthreads();
    if (tid < 2) {
      int c = bid*2 + tid;
      const float* gi = gilex + (size_t)t*H3;
      float rr = sigf(gi[c]        + ghv[tid]);
      float zz = sigf(gi[HH + c]   + ghv[2 + tid]);
      float aa = tanhf(gi[2*HH + c] + rr*ghv[4 + tid]);
      lexh[(size_t)t*HH + c] = (1.f - zz)*aa + zz*hp[c];
    }
    gbar(snc, snc + 1);
  }

  // ---------------- P2a: syn_hids -> diagonal cells ----------------
  for (int task = gw; task < NTOK*HH; task += NBLK*4) {
    int t = task >> 9, r = task & (HH - 1);
    float v = dot512(posW + (size_t)r*HH, lexh + (size_t)t*HH) + posb[r];
    if (lane == 0) cH[(size_t)cid(t,t)*HH + r] = v;
  }
  gbar(snc, snc + 1);

  // ---------------- P2b: diag giW + gR ----------------
  for (int task = gw; task < NTOK*2048; task += NBLK*4) {
    int t = task >> 11, r = task & 2047;
    int cc = cid(t, t);
    const float* hc = cH + (size_t)cc*HH;
    if (r < H3) {
      float v = dot512(synWih + (size_t)r*HH, hc) + synbih[r];
      if (lane == 0) cGIW[(size_t)cc*H3 + r] = v;
    } else {
      float v = dot512(composW + (size_t)(r - H3)*HH, hc);
      if (lane == 0) cGR[(size_t)cc*HH + (r - H3)] = v;
    }
  }
  gbar(snc, snc + 1);

  // ---------------- P2c: diag hAc + ghA ----------------
  {
    int s = bid >> 2, q = bid & 3;       // 64 cells x 4 blocks
    int cc = cid(s, s);
    const float* giw = cGIW + (size_t)cc*H3;
    for (int c = tid; c < HH; c += NTHR) {
      float rr = sigf(giw[c]        + synbhh[c]);
      float zz = sigf(giw[HH + c]   + synbhh[HH + c]);
      float aa = tanhf(giw[2*HH + c] + rr*synbhh[2*HH + c]);
      float ha = (1.f - zz)*aa;
      sv[c] = ha;
      if (q == 0) cHA[(size_t)cc*HH + c] = ha;
    }
    __syncthreads();
    for (int r = q*384 + wv; r < (q+1)*384; r += 4) {
      float v = dot512(synWhh + (size_t)r*HH, sv) + synbhh[r];
      if (lane == 0) cGHA[(size_t)cc*H3 + r] = v;
    }
  }
  gbar(snc, snc + 1);

  // ---------------- chart levels ----------------
  for (int l = 1; l < NTOK; ++l) {
    const int S  = NTOK - l;
    const int nq = NBLK / S;
    const int s  = bid / nq, q = bid % nq;
    if (s < S) {
      const int i = s, j = i + l;
      // scores over splits m
      for (int m = wv; m < l; m += 4) {
        int clft = cid(i, i+m), crgt = cid(i+m+1, j);
        float co = dot512(cH + (size_t)clft*HH, cGR + (size_t)crgt*HH);
        float v  = lp[i*64 + (i+m)] + lp[(i+m+1)*64 + j] + logsigf(co);
        if (lane == 0) ssc[m] = v;
      }
      __syncthreads();
      if (tid == 0) {
        float best = ssc[0]; int kb = 0;
        for (int m = 1; m < l; ++m) if (ssc[m] > best) { best = ssc[m]; kb = m; }
        skb = kb; sbest = best;
      }
      __syncthreads();
      const int kb = skb;
      const int c1 = cid(i, i+kb), c2 = cid(i+kb+1, j), cn = cid(i, j);
      if (q == 0 && tid == 0) lp[i*64 + j] = sbest;
      // hB fully elementwise from precomputed giW/ghA/hAc (redundant per q-block)
      const float* giw2 = cGIW + (size_t)c2*H3;
      const float* gha1 = cGHA + (size_t)c1*H3;
      const float* ha1  = cHA  + (size_t)c1*HH;
      for (int c = tid; c < HH; c += NTHR) {
        float rr = sigf(giw2[c]        + gha1[c]);
        float zz = sigf(giw2[HH + c]   + gha1[HH + c]);
        float aa = tanhf(giw2[2*HH + c] + rr*gha1[2*HH + c]);
        float hb = (1.f - zz)*aa + zz*ha1[c];
        sv[c] = hb;
        if (q == 0) cH[(size_t)cn*HH + c] = hb;
      }
      __syncthreads();
      // new cell giW + gR (row-partitioned across the nq blocks)
      const int RG  = (H3 + nq - 1) / nq;
      const int RG2 = (HH + nq - 1) / nq;
      int re = min(H3, (q+1)*RG);
      for (int r = q*RG + wv; r < re; r += 4) {
        float v = dot512(synWih + (size_t)r*HH, sv) + synbih[r];
        if (lane == 0) cGIW[(size_t)cn*H3 + r] = v;
      }
      re = min(HH, (q+1)*RG2);
      for (int r = q*RG2 + wv; r < re; r += 4) {
        float v = dot512(composW + (size_t)r*HH, sv);
        if (lane == 0) cGR[(size_t)cn*HH + r] = v;
      }
    }
    gbar(snc, snc + 1);

    if (l < NTOK - 1) {   // D2: hAc + ghA for the new level's cells
      const int nb = NBLK / S;
      const int s2 = bid / nb, q2 = bid % nb;
      if (s2 < S) {
        const int cn = cid(s2, s2 + l);
        const float* giw = cGIW + (size_t)cn*H3;
        for (int c = tid; c < HH; c += NTHR) {
          float rr = sigf(giw[c]        + synbhh[c]);
          float zz = sigf(giw[HH + c]   + synbhh[HH + c]);
          float aa = tanhf(giw[2*HH + c] + rr*synbhh[2*HH + c]);
          float ha = (1.f - zz)*aa;
          sv[c] = ha;
          if (q2 == 0) cHA[(size_t)cn*HH + c] = ha;
        }
        __syncthreads();
        const int RH = (H3 + nb - 1) / nb;
        int re = min(H3, (q2+1)*RH);
        for (int r = q2*RH + wv; r < re; r += 4) {
          float v = dot512(synWhh + (size_t)r*HH, sv) + synbhh[r];
          if (lane == 0) cGHA[(size_t)cn*H3 + r] = v;
        }
      }
      gbar(snc, snc + 1);
    }
  }
}

// ---------------- k2: logits GEMM + column log_softmax ----------------
__global__ __launch_bounds__(256, 1) void pcfg_k2(const float* __restrict__ emb,
                                                  const float* __restrict__ ws,
                                                  float* __restrict__ out)
{
  __shared__ __align__(16) float As[64*68];
  __shared__ __align__(16) float Bs[64*68];
  __shared__ float Ts[64*68];
  __shared__ float colm[64], coll[64];
  __shared__ float part[4*64];
  const int tid = threadIdx.x;
  const long vb = (long)blockIdx.x * 64;
  const float* lexh = ws + OFF_LEXH;
  float acc[4][4] = {};
  const int cg = (tid & 15) * 4;   // 4 vocab cols
  const int rg = (tid >> 4) * 4;   // 4 token rows

  for (int kc = 0; kc < HH; kc += 64) {
    __syncthreads();
    for (int e = tid; e < 4096; e += 256) {
      int r = e >> 6, k = e & 63;
      As[r*68 + k] = lexh[(size_t)r*HH + kc + k];
      long v = vb + r;
      Bs[r*68 + k] = (v < VOCAB) ? emb[(size_t)v*HH + kc + k] : 0.f;
    }
    __syncthreads();
#pragma unroll
    for (int k4 = 0; k4 < 16; ++k4) {
      float4 av[4], bv[4];
#pragma unroll
      for (int ii = 0; ii < 4; ++ii) {
        av[ii] = *(const float4*)&As[(rg+ii)*68 + k4*4];
        bv[ii] = *(const float4*)&Bs[(cg+ii)*68 + k4*4];
      }
#pragma unroll
      for (int ii = 0; ii < 4; ++ii)
#pragma unroll
        for (int jj = 0; jj < 4; ++jj)
          acc[ii][jj] += av[ii].x*bv[jj].x + av[ii].y*bv[jj].y
                       + av[ii].z*bv[jj].z + av[ii].w*bv[jj].w;
    }
  }
  // stage logits tile Ts[row][col]
#pragma unroll
  for (int ii = 0; ii < 4; ++ii)
#pragma unroll
    for (int jj = 0; jj < 4; ++jj)
      Ts[(rg+ii)*68 + (cg+jj)] = acc[ii][jj];
  __syncthreads();

  {  // column max over 64 rows (softmax axis = token axis)
    int c = tid & 63, qq = tid >> 6;
    float m = -1e30f;
    for (int r = qq*16; r < qq*16 + 16; ++r) m = fmaxf(m, Ts[r*68 + c]);
    part[qq*64 + c] = m;
  }
  __syncthreads();
  if (tid < 64)
    colm[tid] = fmaxf(fmaxf(part[tid], part[64+tid]), fmaxf(part[128+tid], part[192+tid]));
  __syncthreads();
  {
    int c = tid & 63, qq = tid >> 6;
    float m = colm[c], ssum = 0.f;
    for (int r = qq*16; r < qq*16 + 16; ++r) ssum += expf(Ts[r*68 + c] - m);
    part[qq*64 + c] = ssum;
  }
  __syncthreads();
  if (tid < 64)
    coll[tid] = logf(part[tid] + part[64+tid] + part[128+tid] + part[192+tid]);
  __syncthreads();

  const int valid = (int)min((long)64, (long)VOCAB - vb);
  {  // coalesced writes: lane = column
    int c = tid & 63, qq = tid >> 6;
    for (int r = qq*16; r < qq*16 + 16; ++r) {
      float v = Ts[r*68 + c] - colm[c] - coll[c];
      if (c < valid) out[(size_t)r*VOCAB + vb + c] = v;
    }
  }
  __syncthreads();
  if (tid < 64) {  // per-row max partial (ordered-uint atomicMax)
    int r = tid;
    float m = -1e30f;
    for (int c = 0; c < valid; ++c) m = fmaxf(m, Ts[r*68 + c] - colm[c] - coll[c]);
    unsigned b = __float_as_uint(m);
    unsigned enc = (b & 0x80000000u) ? ~b : (b | 0x80000000u);
    atomicMax((unsigned*)(ws + OFF_ROWMAX) + r, enc);
  }
}

__global__ void pcfg_k3(const float* __restrict__ ws, float* __restrict__ out) {
  const int tid = threadIdx.x;
  const unsigned* rm = (const unsigned*)(ws + OFF_ROWMAX);
  float v = 0.f;
  if (tid < 64) {
    unsigned u = rm[tid];
    unsigned b = (u & 0x80000000u) ? (u ^ 0x80000000u) : ~u;
    v = __uint_as_float(b);
  }
  float s = v;
#pragma unroll
  for (int off = 32; off >= 1; off >>= 1) s += __shfl_xor(s, off);
  if (tid == 0) {
    out[(size_t)NTOK*VOCAB]     = ws[OFF_LP + 63];  // chart_lp[0][63]
    out[(size_t)NTOK*VOCAB + 1] = s;                // sum of per-row maxima
  }
}

extern "C" void kernel_launch(void* const* d_in, const int* in_sizes, int n_in,
                              void* d_out, int out_size, void* d_ws, size_t ws_size,
                              hipStream_t stream) {
  (void)in_sizes; (void)n_in; (void)out_size;
  const int*   tokens = (const int*)  d_in[0];
  const float* emb    = (const float*)d_in[1];
  const float* lexWih = (const float*)d_in[2];
  const float* lexWhh = (const float*)d_in[3];
  const float* lexbih = (const float*)d_in[4];
  const float* lexbhh = (const float*)d_in[5];
  const float* posW   = (const float*)d_in[6];
  const float* posb   = (const float*)d_in[7];
  const float* synWih = (const float*)d_in[8];
  const float* synWhh = (const float*)d_in[9];
  const float* synbih = (const float*)d_in[10];
  const float* synbhh = (const float*)d_in[11];
  const float* composW= (const float*)d_in[12];
  float* ws  = (float*)d_ws;
  float* out = (float*)d_out;

  if (ws_size < (size_t)WS_FLOATS * sizeof(float)) return;  // ~38.9 MB needed

  hipMemsetAsync((char*)d_ws + (size_t)OFF_SYNC * sizeof(float), 0,
                 64 * sizeof(float), stream);
  pcfg_k1<<<NBLK, NTHR, 0, stream>>>(tokens, emb, lexWih, lexWhh, lexbih, lexbhh,
                                     posW, posb, synWih, synWhh, synbih, synbhh,
                                     composW, ws);
  pcfg_k2<<<(VOCAB + 63)/64, 256, 0, stream>>>(emb, ws, out);
  pcfg_k3<<<1, 64, 0, stream>>>(ws, out);
}

// Round 5
// 5880.960 us; speedup vs baseline: 1.7126x; 1.7126x over previous
//
#include <hip/hip_runtime.h>
#include <cstdint>
#include <cstddef>

// ---------------------------------------------------------------------------
// PCFG-RNN forward on MI355X — round 2 design (resubmit #3; broker timeouts).
// k1: persistent 256-block x 1024-thread kernel (16 waves/block, 4 waves/SIMD).
//     P0 (embed gather + gi_lex GEMM) -> 64 sequential lex-GRU steps on a
//     64-block sub-barrier -> P2 (diag-cell precompute) -> 63 chart levels
//     x 2 phases. Per-cell precompute (gR, giW, hAc, ghA) makes hB fully
//     elementwise. GEMVs use paired dots (dot512x2) with the h-vector staged
//     in LDS: halves b-loads, doubles load ILP.
// k2: tiled 64x64 GEMM lex_hids @ emb^T + column log_softmax.
// k3: final scalars.
// ---------------------------------------------------------------------------

#define NBLK 256
#define NTHR 1024
#define LEXB 64
#define HH   512
#define H3   1536
#define NTOK 64
#define VOCAB 50257
#define NCELLS 2080

// ---- ws layout (float offsets) ----
#define OFF_LP      0                          // 64*64 chart log-probs (zeroed)
#define OFF_H0      4096                       // 512 zeros
#define OFF_GILEX   4608                       // 64*1536
#define OFF_LEXH    (OFF_GILEX + NTOK*H3)      // 64*512
#define OFF_ROWMAX  (OFF_LEXH + NTOK*HH)       // 64 (as uint, ordered encoding)
#define OFF_SYNC    (OFF_ROWMAX + 64)          // [0,1]=global cnt/gen [2,3]=lex
#define OFF_CELLH   (OFF_SYNC + 64)
#define OFF_CELLGR  (OFF_CELLH  + NCELLS*HH)
#define OFF_CELLHA  (OFF_CELLGR + NCELLS*HH)
#define OFF_CELLGIW (OFF_CELLHA + NCELLS*HH)
#define OFF_CELLGHA (OFF_CELLGIW + NCELLS*H3)
#define WS_FLOATS   (OFF_CELLGHA + NCELLS*H3)  // ~9.72M floats = ~38.9 MB

__device__ __forceinline__ int cid(int i, int j) { return ((j*(j+1)) >> 1) + i; }

__device__ __forceinline__ float sigf(float x) { return 1.f / (1.f + expf(-x)); }

__device__ __forceinline__ float logsigf(float x) {
  return fminf(x, 0.f) - log1pf(expf(-fabsf(x)));
}

__device__ __forceinline__ float wredsum(float s) {
#pragma unroll
  for (int off = 32; off >= 1; off >>= 1) s += __shfl_xor(s, off);
  return s;
}

// one 512-dot per wave; result on all lanes
__device__ __forceinline__ float dot512(const float* __restrict__ a,
                                        const float* __restrict__ b) {
  const int lane = threadIdx.x & 63;
  const float4* a4 = (const float4*)a;
  const float4* b4 = (const float4*)b;
  float4 x0 = a4[lane], x1 = a4[lane + 64];
  float4 y0 = b4[lane], y1 = b4[lane + 64];
  float s = x0.x*y0.x + x0.y*y0.y + x0.z*y0.z + x0.w*y0.w
          + x1.x*y1.x + x1.y*y1.y + x1.z*y1.z + x1.w*y1.w;
  return wredsum(s);
}

// two 512-dots sharing the b vector (LDS-staged): halves b loads, 2x load ILP
__device__ __forceinline__ void dot512x2(const float* __restrict__ a0,
                                         const float* __restrict__ a1,
                                         const float* __restrict__ b,
                                         float& r0, float& r1) {
  const int lane = threadIdx.x & 63;
  const float4* A0 = (const float4*)a0;
  const float4* A1 = (const float4*)a1;
  const float4* B  = (const float4*)b;
  float4 b0 = B[lane], b1 = B[lane + 64];
  float4 x0 = A0[lane], x1 = A0[lane + 64];
  float4 y0 = A1[lane], y1 = A1[lane + 64];
  float s0 = x0.x*b0.x + x0.y*b0.y + x0.z*b0.z + x0.w*b0.w
           + x1.x*b1.x + x1.y*b1.y + x1.z*b1.z + x1.w*b1.w;
  float s1 = y0.x*b0.x + y0.y*b0.y + y0.z*b0.z + y0.w*b0.w
           + y1.x*b1.x + y1.y*b1.y + y1.z*b1.z + y1.w*b1.w;
#pragma unroll
  for (int off = 32; off >= 1; off >>= 1) {
    s0 += __shfl_xor(s0, off);
    s1 += __shfl_xor(s1, off);
  }
  r0 = s0; r1 = s1;
}

// software grid barrier over n blocks (generation-tagged)
__device__ __forceinline__ void gbarN(int* cnt, int* gen, int n) {
  __syncthreads();
  if (threadIdx.x == 0) {
    __threadfence();
    int g = __hip_atomic_load(gen, __ATOMIC_RELAXED, __HIP_MEMORY_SCOPE_AGENT);
    int p = __hip_atomic_fetch_add(cnt, 1, __ATOMIC_ACQ_REL, __HIP_MEMORY_SCOPE_AGENT);
    if (p == n - 1) {
      __hip_atomic_store(cnt, 0, __ATOMIC_RELAXED, __HIP_MEMORY_SCOPE_AGENT);
      __hip_atomic_fetch_add(gen, 1, __ATOMIC_RELEASE, __HIP_MEMORY_SCOPE_AGENT);
    } else {
      while (__hip_atomic_load(gen, __ATOMIC_RELAXED, __HIP_MEMORY_SCOPE_AGENT) == g)
        __builtin_amdgcn_s_sleep(1);
    }
    __threadfence();
  }
  __syncthreads();
}

__global__ __launch_bounds__(NTHR, 1) void pcfg_k1(
    const int* __restrict__ tokens, const float* __restrict__ emb,
    const float* __restrict__ lexWih, const float* __restrict__ lexWhh,
    const float* __restrict__ lexbih, const float* __restrict__ lexbhh,
    const float* __restrict__ posW,   const float* __restrict__ posb,
    const float* __restrict__ synWih, const float* __restrict__ synWhh,
    const float* __restrict__ synbih, const float* __restrict__ synbhh,
    const float* __restrict__ composW, float* __restrict__ ws)
{
  __shared__ __align__(16) float sv[HH];   // staged h-vector
  __shared__ float ssc[64];                // split scores
  __shared__ float ghv[24];                // lex gh values (8 cols x 3 gates)
  __shared__ int   skb;
  __shared__ float sbest;

  float* lp    = ws + OFF_LP;
  float* h0    = ws + OFF_H0;
  float* gilex = ws + OFF_GILEX;
  float* lexh  = ws + OFF_LEXH;
  unsigned* rowmax = (unsigned*)(ws + OFF_ROWMAX);
  int*   snc   = (int*)(ws + OFF_SYNC);
  float* cH   = ws + OFF_CELLH;
  float* cGR  = ws + OFF_CELLGR;
  float* cHA  = ws + OFF_CELLHA;
  float* cGIW = ws + OFF_CELLGIW;
  float* cGHA = ws + OFF_CELLGHA;

  const int bid = blockIdx.x, tid = threadIdx.x;
  const int wv = tid >> 6, lane = tid & 63;

  // ---------------- P0: zero lp/h0, rowmax init, gi_lex GEMM ----------------
  {
    for (int i = bid*NTHR + tid; i < OFF_GILEX; i += NBLK*NTHR) ws[i] = 0.f;
    if (bid == 0 && tid < 64) rowmax[tid] = 0u;
    const int s = bid >> 2, q = bid & 3;          // 4 blocks per token
    const int tok = tokens[s];
    if (tid < HH) sv[tid] = emb[(size_t)tok*HH + tid];
    __syncthreads();
    for (int r = q*384 + wv*2; r < (q+1)*384; r += 32) {
      float v0, v1;
      dot512x2(lexWih + (size_t)r*HH, lexWih + (size_t)(r+1)*HH, sv, v0, v1);
      if (lane == 0) {
        gilex[(size_t)s*H3 + r]     = v0 + lexbih[r];
        gilex[(size_t)s*H3 + r + 1] = v1 + lexbih[r + 1];
      }
    }
  }
  gbarN(snc, snc + 1, NBLK);

  // ---------------- P1: 64 sequential lex GRU steps (64-block sub-barrier) --
  if (bid < LEXB) {
    for (int t = 0; t < NTOK; ++t) {
      const float* hp = (t == 0) ? h0 : (lexh + (size_t)(t-1)*HH);
      // 8 columns per block, 3 gates -> 24 dots; d = gate*8 + cl
      for (int d = wv; d < 24; d += 16) {
        int gate = d >> 3, cl = d & 7;
        int row = gate*HH + bid*8 + cl;
        float v = dot512(lexWhh + (size_t)row*HH, hp) + lexbhh[row];
        if (lane == 0) ghv[d] = v;
      }
      __syncthreads();
      if (tid < 8) {
        int c = bid*8 + tid;
        const float* gi = gilex + (size_t)t*H3;
        float rr = sigf(gi[c]         + ghv[tid]);
        float zz = sigf(gi[HH + c]    + ghv[8 + tid]);
        float aa = tanhf(gi[2*HH + c] + rr*ghv[16 + tid]);
        lexh[(size_t)t*HH + c] = (1.f - zz)*aa + zz*hp[c];
      }
      gbarN(snc + 2, snc + 3, LEXB);
    }
  }
  gbarN(snc, snc + 1, NBLK);   // join: non-lex blocks park here

  // ---------------- P2a: syn_hids -> diagonal cells ----------------
  {
    const int s = bid >> 2, q = bid & 3;          // 4 blocks per token
    if (tid < HH) sv[tid] = lexh[(size_t)s*HH + tid];
    __syncthreads();
    for (int r = q*128 + wv*2; r < (q+1)*128; r += 32) {
      float v0, v1;
      dot512x2(posW + (size_t)r*HH, posW + (size_t)(r+1)*HH, sv, v0, v1);
      if (lane == 0) {
        cH[(size_t)cid(s,s)*HH + r]     = v0 + posb[r];
        cH[(size_t)cid(s,s)*HH + r + 1] = v1 + posb[r + 1];
      }
    }
  }
  gbarN(snc, snc + 1, NBLK);

  // ---------------- P2b: diag giW + gR ----------------
  {
    const int s = bid >> 2, q = bid & 3;
    const int cc = cid(s, s);
    if (tid < HH) sv[tid] = cH[(size_t)cc*HH + tid];
    __syncthreads();
    if (q < 3) {   // synWih rows [q*512, (q+1)*512)
      for (int r = q*HH + wv*2; r < (q+1)*HH; r += 32) {
        float v0, v1;
        dot512x2(synWih + (size_t)r*HH, synWih + (size_t)(r+1)*HH, sv, v0, v1);
        if (lane == 0) {
          cGIW[(size_t)cc*H3 + r]     = v0 + synbih[r];
          cGIW[(size_t)cc*H3 + r + 1] = v1 + synbih[r + 1];
        }
      }
    } else {       // composW rows
      for (int r = wv*2; r < HH; r += 32) {
        float v0, v1;
        dot512x2(composW + (size_t)r*HH, composW + (size_t)(r+1)*HH, sv, v0, v1);
        if (lane == 0) {
          cGR[(size_t)cc*HH + r]     = v0;
          cGR[(size_t)cc*HH + r + 1] = v1;
        }
      }
    }
  }
  gbarN(snc, snc + 1, NBLK);

  // ---------------- P2c: diag hAc + ghA ----------------
  {
    const int s = bid >> 2, q = bid & 3;
    const int cc = cid(s, s);
    const float* giw = cGIW + (size_t)cc*H3;
    if (tid < HH) {
      int c = tid;
      float rr = sigf(giw[c]         + synbhh[c]);
      float zz = sigf(giw[HH + c]    + synbhh[HH + c]);
      float aa = tanhf(giw[2*HH + c] + rr*synbhh[2*HH + c]);
      float ha = (1.f - zz)*aa;
      sv[c] = ha;
      if (q == 0) cHA[(size_t)cc*HH + c] = ha;
    }
    __syncthreads();
    for (int r = q*384 + wv*2; r < (q+1)*384; r += 32) {
      float v0, v1;
      dot512x2(synWhh + (size_t)r*HH, synWhh + (size_t)(r+1)*HH, sv, v0, v1);
      if (lane == 0) {
        cGHA[(size_t)cc*H3 + r]     = v0 + synbhh[r];
        cGHA[(size_t)cc*H3 + r + 1] = v1 + synbhh[r + 1];
      }
    }
  }
  gbarN(snc, snc + 1, NBLK);

  // ---------------- chart levels ----------------
  for (int l = 1; l < NTOK; ++l) {
    const int S  = NTOK - l;
    const int nq = NBLK / S;
    const int s  = bid / nq, q = bid - s*nq;
    if (s < S) {
      const int i = s, j = i + l;
      // scores over splits m (computed redundantly by each q-block)
#pragma unroll 2
      for (int m = wv; m < l; m += 16) {
        int clft = cid(i, i+m), crgt = cid(i+m+1, j);
        float co = dot512(cH + (size_t)clft*HH, cGR + (size_t)crgt*HH);
        float v  = lp[i*64 + (i+m)] + lp[(i+m+1)*64 + j] + logsigf(co);
        if (lane == 0) ssc[m] = v;
      }
      __syncthreads();
      if (wv == 0) {   // wave-parallel first-max argmax
        float v = (lane < l) ? ssc[lane] : -3.4e38f;
        int idx = lane;
#pragma unroll
        for (int off = 32; off >= 1; off >>= 1) {
          float ov = __shfl_xor(v, off);
          int   oi = __shfl_xor(idx, off);
          if (ov > v || (ov == v && oi < idx)) { v = ov; idx = oi; }
        }
        if (lane == 0) { skb = idx; sbest = v; }
      }
      __syncthreads();
      const int kb = skb;
      const int c1 = cid(i, i+kb), c2 = cid(i+kb+1, j), cn = cid(i, j);
      if (q == 0 && tid == 0) lp[i*64 + j] = sbest;
      if (l < NTOK - 1) {
        // hB fully elementwise from precomputed giW/ghA/hAc
        const float* giw2 = cGIW + (size_t)c2*H3;
        const float* gha1 = cGHA + (size_t)c1*H3;
        const float* ha1  = cHA  + (size_t)c1*HH;
        if (tid < HH) {
          int c = tid;
          float rr = sigf(giw2[c]         + gha1[c]);
          float zz = sigf(giw2[HH + c]    + gha1[HH + c]);
          float aa = tanhf(giw2[2*HH + c] + rr*gha1[2*HH + c]);
          float hb = (1.f - zz)*aa + zz*ha1[c];
          sv[c] = hb;
          if (q == 0) cH[(size_t)cn*HH + c] = hb;
        }
        __syncthreads();
        // new-cell giW + gR, row-partitioned across the nq blocks
        const int RG  = (H3 + nq - 1) / nq;
        {
          const int base = q*RG, re = min(H3, base + RG);
          for (int r = base + wv*2; r < re; r += 32) {
            if (r + 1 < re) {
              float v0, v1;
              dot512x2(synWih + (size_t)r*HH, synWih + (size_t)(r+1)*HH, sv, v0, v1);
              if (lane == 0) {
                cGIW[(size_t)cn*H3 + r]     = v0 + synbih[r];
                cGIW[(size_t)cn*H3 + r + 1] = v1 + synbih[r + 1];
              }
            } else {
              float v = dot512(synWih + (size_t)r*HH, sv) + synbih[r];
              if (lane == 0) cGIW[(size_t)cn*H3 + r] = v;
            }
          }
        }
        {
          const int RG2 = (HH + nq - 1) / nq;
          const int base = q*RG2, re = min(HH, base + RG2);
          for (int r = base + wv*2; r < re; r += 32) {
            if (r + 1 < re) {
              float v0, v1;
              dot512x2(composW + (size_t)r*HH, composW + (size_t)(r+1)*HH, sv, v0, v1);
              if (lane == 0) {
                cGR[(size_t)cn*HH + r]     = v0;
                cGR[(size_t)cn*HH + r + 1] = v1;
              }
            } else {
              float v = dot512(composW + (size_t)r*HH, sv);
              if (lane == 0) cGR[(size_t)cn*HH + r] = v;
            }
          }
        }
      }
    }
    gbarN(snc, snc + 1, NBLK);

    if (l < NTOK - 1) {   // D2: hAc + ghA for the new level's cells
      const int nb = NBLK / S;
      const int s2 = bid / nb, q2 = bid - s2*nb;
      if (s2 < S) {
        const int cn = cid(s2, s2 + l);
        const float* giw = cGIW + (size_t)cn*H3;
        if (tid < HH) {
          int c = tid;
          float rr = sigf(giw[c]         + synbhh[c]);
          float zz = sigf(giw[HH + c]    + synbhh[HH + c]);
          float aa = tanhf(giw[2*HH + c] + rr*synbhh[2*HH + c]);
          float ha = (1.f - zz)*aa;
          sv[c] = ha;
          if (q2 == 0) cHA[(size_t)cn*HH + c] = ha;
        }
        __syncthreads();
        const int RH = (H3 + nb - 1) / nb;
        const int base = q2*RH, re = min(H3, base + RH);
        for (int r = base + wv*2; r < re; r += 32) {
          if (r + 1 < re) {
            float v0, v1;
            dot512x2(synWhh + (size_t)r*HH, synWhh + (size_t)(r+1)*HH, sv, v0, v1);
            if (lane == 0) {
              cGHA[(size_t)cn*H3 + r]     = v0 + synbhh[r];
              cGHA[(size_t)cn*H3 + r + 1] = v1 + synbhh[r + 1];
            }
          } else {
            float v = dot512(synWhh + (size_t)r*HH, sv) + synbhh[r];
            if (lane == 0) cGHA[(size_t)cn*H3 + r] = v;
          }
        }
      }
      gbarN(snc, snc + 1, NBLK);
    }
  }
}

// ---------------- k2: logits GEMM + column log_softmax ----------------
__global__ __launch_bounds__(256, 1) void pcfg_k2(const float* __restrict__ emb,
                                                  const float* __restrict__ ws,
                                                  float* __restrict__ out)
{
  __shared__ __align__(16) float As[64*68];
  __shared__ __align__(16) float Bs[64*68];
  __shared__ float Ts[64*68];
  __shared__ float colm[64], coll[64];
  __shared__ float part[4*64];
  const int tid = threadIdx.x;
  const long vb = (long)blockIdx.x * 64;
  const float* lexh = ws + OFF_LEXH;
  float acc[4][4] = {};
  const int cg = (tid & 15) * 4;   // 4 vocab cols
  const int rg = (tid >> 4) * 4;   // 4 token rows

  for (int kc = 0; kc < HH; kc += 64) {
    __syncthreads();
    for (int e = tid; e < 4096; e += 256) {
      int r = e >> 6, k = e & 63;
      As[r*68 + k] = lexh[(size_t)r*HH + kc + k];
      long v = vb + r;
      Bs[r*68 + k] = (v < VOCAB) ? emb[(size_t)v*HH + kc + k] : 0.f;
    }
    __syncthreads();
#pragma unroll
    for (int k4 = 0; k4 < 16; ++k4) {
      float4 av[4], bv[4];
#pragma unroll
      for (int ii = 0; ii < 4; ++ii) {
        av[ii] = *(const float4*)&As[(rg+ii)*68 + k4*4];
        bv[ii] = *(const float4*)&Bs[(cg+ii)*68 + k4*4];
      }
#pragma unroll
      for (int ii = 0; ii < 4; ++ii)
#pragma unroll
        for (int jj = 0; jj < 4; ++jj)
          acc[ii][jj] += av[ii].x*bv[jj].x + av[ii].y*bv[jj].y
                       + av[ii].z*bv[jj].z + av[ii].w*bv[jj].w;
    }
  }
#pragma unroll
  for (int ii = 0; ii < 4; ++ii)
#pragma unroll
    for (int jj = 0; jj < 4; ++jj)
      Ts[(rg+ii)*68 + (cg+jj)] = acc[ii][jj];
  __syncthreads();

  {  // column max over 64 rows (softmax axis = token axis)
    int c = tid & 63, qq = tid >> 6;
    float m = -1e30f;
    for (int r = qq*16; r < qq*16 + 16; ++r) m = fmaxf(m, Ts[r*68 + c]);
    part[qq*64 + c] = m;
  }
  __syncthreads();
  if (tid < 64)
    colm[tid] = fmaxf(fmaxf(part[tid], part[64+tid]), fmaxf(part[128+tid], part[192+tid]));
  __syncthreads();
  {
    int c = tid & 63, qq = tid >> 6;
    float m = colm[c], ssum = 0.f;
    for (int r = qq*16; r < qq*16 + 16; ++r) ssum += expf(Ts[r*68 + c] - m);
    part[qq*64 + c] = ssum;
  }
  __syncthreads();
  if (tid < 64)
    coll[tid] = logf(part[tid] + part[64+tid] + part[128+tid] + part[192+tid]);
  __syncthreads();

  const int valid = (int)min((long)64, (long)VOCAB - vb);
  {  // coalesced writes: lane = column
    int c = tid & 63, qq = tid >> 6;
    for (int r = qq*16; r < qq*16 + 16; ++r) {
      float v = Ts[r*68 + c] - colm[c] - coll[c];
      if (c < valid) out[(size_t)r*VOCAB + vb + c] = v;
    }
  }
  __syncthreads();
  if (tid < 64) {  // per-row max partial (ordered-uint atomicMax)
    int r = tid;
    float m = -1e30f;
    for (int c = 0; c < valid; ++c) m = fmaxf(m, Ts[r*68 + c] - colm[c] - coll[c]);
    unsigned b = __float_as_uint(m);
    unsigned enc = (b & 0x80000000u) ? ~b : (b | 0x80000000u);
    atomicMax((unsigned*)(ws + OFF_ROWMAX) + r, enc);
  }
}

__global__ void pcfg_k3(const float* __restrict__ ws, float* __restrict__ out) {
  const int tid = threadIdx.x;
  const unsigned* rm = (const unsigned*)(ws + OFF_ROWMAX);
  float v = 0.f;
  if (tid < 64) {
    unsigned u = rm[tid];
    unsigned b = (u & 0x80000000u) ? (u ^ 0x80000000u) : ~u;
    v = __uint_as_float(b);
  }
  float s = v;
#pragma unroll
  for (int off = 32; off >= 1; off >>= 1) s += __shfl_xor(s, off);
  if (tid == 0) {
    out[(size_t)NTOK*VOCAB]     = ws[OFF_LP + 63];  // chart_lp[0][63]
    out[(size_t)NTOK*VOCAB + 1] = s;                // sum of per-row maxima
  }
}

extern "C" void kernel_launch(void* const* d_in, const int* in_sizes, int n_in,
                              void* d_out, int out_size, void* d_ws, size_t ws_size,
                              hipStream_t stream) {
  (void)in_sizes; (void)n_in; (void)out_size;
  const int*   tokens = (const int*)  d_in[0];
  const float* emb    = (const float*)d_in[1];
  const float* lexWih = (const float*)d_in[2];
  const float* lexWhh = (const float*)d_in[3];
  const float* lexbih = (const float*)d_in[4];
  const float* lexbhh = (const float*)d_in[5];
  const float* posW   = (const float*)d_in[6];
  const float* posb   = (const float*)d_in[7];
  const float* synWih = (const float*)d_in[8];
  const float* synWhh = (const float*)d_in[9];
  const float* synbih = (const float*)d_in[10];
  const float* synbhh = (const float*)d_in[11];
  const float* composW= (const float*)d_in[12];
  float* ws  = (float*)d_ws;
  float* out = (float*)d_out;

  if (ws_size < (size_t)WS_FLOATS * sizeof(float)) return;  // ~38.9 MB needed

  hipMemsetAsync((char*)d_ws + (size_t)OFF_SYNC * sizeof(float), 0,
                 64 * sizeof(float), stream);
  pcfg_k1<<<NBLK, NTHR, 0, stream>>>(tokens, emb, lexWih, lexWhh, lexbih, lexbhh,
                                     posW, posb, synWih, synWhh, synbih, synbhh,
                                     composW, ws);
  pcfg_k2<<<(VOCAB + 63)/64, 256, 0, stream>>>(emb, ws, out);
  pcfg_k3<<<1, 64, 0, stream>>>(ws, out);
}